// Round 1
// 472.838 us; speedup vs baseline: 1.1364x; 1.1364x over previous
//
#include <hip/hip_runtime.h>
#include <hip/hip_bf16.h>
#include <stdint.h>
#include <math.h>

typedef unsigned short u16;
typedef unsigned int   u32;
typedef __attribute__((ext_vector_type(8))) __bf16 bf16x8;   // 4 VGPRs: MFMA A/B frag
typedef __attribute__((ext_vector_type(8))) u16    u16x8;
typedef __attribute__((ext_vector_type(4))) float  f32x4;

// ---------------------------------------------------------------------------
// fp32 -> bf16 (round-to-nearest-even)
__device__ __forceinline__ u16 f2bf_rne(float f) {
    u32 u = __float_as_uint(f);
    u += 0x7fffu + ((u >> 16) & 1u);
    return (u16)(u >> 16);
}

// sign(w) in bf16: w > 0 ? +1.0 : -1.0  (matches jnp.where(x > 0, 1, -1))
__device__ __forceinline__ u16 signbf(float f) {
    return (f > 0.0f) ? (u16)0x3F80u : (u16)0xBF80u;
}

// Single launch: x -> bf16(rne), w -> sign bf16 (+-1). Both vectorized x8.
__global__ void cvt_both(const float* __restrict__ x, const float* __restrict__ w,
                         u16* __restrict__ xb, u16* __restrict__ wb,
                         long nx, long nw)
{
    long i0 = ((long)blockIdx.x * blockDim.x + threadIdx.x) * 8;
    long stride = (long)gridDim.x * blockDim.x * 8;
    for (long i = i0; i < nx; i += stride) {
        f32x4 a = *(const f32x4*)(x + i);
        f32x4 b = *(const f32x4*)(x + i + 4);
        u16x8 o;
        o[0] = f2bf_rne(a[0]); o[1] = f2bf_rne(a[1]);
        o[2] = f2bf_rne(a[2]); o[3] = f2bf_rne(a[3]);
        o[4] = f2bf_rne(b[0]); o[5] = f2bf_rne(b[1]);
        o[6] = f2bf_rne(b[2]); o[7] = f2bf_rne(b[3]);
        *(u16x8*)(xb + i) = o;
    }
    for (long i = i0; i < nw; i += stride) {
        f32x4 a = *(const f32x4*)(w + i);
        f32x4 b = *(const f32x4*)(w + i + 4);
        u16x8 o;
        o[0] = signbf(a[0]); o[1] = signbf(a[1]);
        o[2] = signbf(a[2]); o[3] = signbf(a[3]);
        o[4] = signbf(b[0]); o[5] = signbf(b[1]);
        o[6] = signbf(b[2]); o[7] = signbf(b[3]);
        *(u16x8*)(wb + i) = o;
    }
}

// ---------------------------------------------------------------------------
// async global -> LDS, 16B per lane. LDS dest must be uniform_base + lane*16.
__device__ __forceinline__ void gload_lds16(const void* g, void* l) {
    __builtin_amdgcn_global_load_lds(
        (const __attribute__((address_space(1))) void*)g,
        (__attribute__((address_space(3))) void*)l, 16, 0, 0);
}

// ===========================================================================
// 256x256 8-phase GEMM (m201-style template in plain HIP).
// C[M][N] = A[M][K](bf16) * B[N][K](bf16)^T * scale.
//
// Geometry: BM=BN=256, BK=64. 512 threads = 8 waves (2 Mwaves x 4 Nwaves);
// each wave owns a 128x64 output tile = 8x4 frags of 16x16x32 MFMA, 2 k-slices.
// LDS 128 KiB: [buf(2)][op A/B][half(128x64)] double-buffered.
//
// Swizzle (T2): within a 128x64 bf16 half-tile, 16B-granule index g (0..7)
// stored at g ^ (row & 7). global_load_lds writes LDS linearly, so the
// SOURCE global address is pre-swizzled (rule #21: both-sides-or-neither).
//
// Phase schedule per iteration (tiles T0=kt0 -> buf0, T1=kt0+1 -> buf1),
// 1 half-tile (2 x global_load_lds dwordx4) staged per phase, ring order
// B0,B1,A0,A1 per tile. Each half-tile is staged >=1 phase after its last
// ds_read (WAR safe via phase-tail barrier); vmcnt(4) at ph4/ph8 keeps
// 2 half-tiles in flight across tile boundaries (never drains to 0 in-loop).
//   ph1: rd A(mh0)+B(nh0) of buf0 | stage T1.A0->buf1 | MFMA Q(0,0)
//   ph2: rd B(nh1)                | stage T1.A1->buf1 | MFMA Q(0,1)
//   ph3: rd A(mh1)                | stage T2.B0->buf0 | MFMA Q(1,1)
//   ph4: --                       | stage T2.B1->buf0 | vmcnt(4) | MFMA Q(1,0)
//   ph5-8: same on buf1, staging T2.A0/A1->buf0, T3.B0/B1->buf1, vmcnt(4) at ph8.
// Last iteration clamps T2/T3 to NT-1 (re-stages valid data into dead slots,
// keeping vmcnt counts exact). Prologue stages T0 fully + T1.B, vmcnt(4).
// ===========================================================================
#define BM 256
#define BN 256
#define BK 64

__global__ __launch_bounds__(512, 2)
void gemm_bt_256(const u16* __restrict__ A, const u16* __restrict__ B,
                 float* __restrict__ C, int M, int N, int K, float scale)
{
    __shared__ u16 lds[2][2][2][8192];   // [buf][A=0/B=1][half][128*64] = 128 KiB

    const int tid  = threadIdx.x;
    const int lane = tid & 63;
    const int wave = tid >> 6;
    const int wr = wave >> 2;            // 0..1: which 128-row half of C tile
    const int wc = wave & 3;             // 0..3: which 64-col strip

    // T1: bijective XCD swizzle (nwg % 8 == 0 here: 512 blocks)
    int wg = blockIdx.x;
    const int nwg = gridDim.x;
    if ((nwg & 7) == 0) wg = (wg & 7) * (nwg >> 3) + (wg >> 3);
    const int nbx = N / BN;
    const int brow = (wg / nbx) * BM;
    const int bcol = (wg % nbx) * BN;

    // Staging source: thread t fills LDS linear bytes [t*16, t*16+16) of a
    // half-tile issue (64 rows x 128B). row = t>>3, stored-granule = t&7;
    // content there must be global granule (t&7) ^ (row&7).
    const int srow = tid >> 3;                    // 0..63
    const int sg   = (tid & 7) ^ (srow & 7);      // pre-swizzled source granule
    const u16* Ag = A + (size_t)(brow + srow) * K + sg * 8;
    const u16* Bg = B + (size_t)(bcol + srow) * K + sg * 8;

    // ds_read bases. A-frag (16x16x32): row = f*16 + (lane&15),
    // k = ks*32 + (lane>>4)*8  ->  granule (ks*4 + lane>>4) ^ (lane&7).
    const int l15 = lane & 15, l7 = lane & 7, lg = lane >> 4;
    const int aoff0 = l15 * 128 + ((lg ^ l7) * 16);         // ks=0, bytes
    const int aoff1 = l15 * 128 + (((4 + lg) ^ l7) * 16);   // ks=1, bytes
    const char* Ah[2] = { (const char*)&lds[0][0][wr][0],
                          (const char*)&lds[1][0][wr][0] };
    const char* Bh[2] = { (const char*)&lds[0][1][wc >> 1][0] + (wc & 1) * 8192,
                          (const char*)&lds[1][1][wc >> 1][0] + (wc & 1) * 8192 };

    f32x4 acc[8][4];
#pragma unroll
    for (int i = 0; i < 8; ++i)
#pragma unroll
        for (int j = 0; j < 4; ++j) acc[i][j] = (f32x4){0.f, 0.f, 0.f, 0.f};

    bf16x8 aF[2][4];       // [ks][frag-within-current-mh]
    bf16x8 bF[2][2][2];    // [nh][ks][frag-within-nh]  (both nh halves live)

#define STAGE_A(buf, half, kt) do {                                          \
    const u16* _s = Ag + (size_t)(half) * 128 * K + (size_t)(kt) * BK;       \
    gload_lds16(_s,                  &lds[buf][0][half][tid * 8]);           \
    gload_lds16(_s + (size_t)64 * K, &lds[buf][0][half][tid * 8 + 4096]);    \
} while (0)

#define STAGE_B(buf, half, kt) do {                                          \
    const u16* _s = Bg + (size_t)(half) * 128 * K + (size_t)(kt) * BK;       \
    gload_lds16(_s,                  &lds[buf][1][half][tid * 8]);           \
    gload_lds16(_s + (size_t)64 * K, &lds[buf][1][half][tid * 8 + 4096]);    \
} while (0)

#define READ_A(buf, mh) do {                                                 \
    _Pragma("unroll") for (int f = 0; f < 4; ++f) {                          \
        aF[0][f] = *(const bf16x8*)(Ah[buf] + ((mh)*4 + f) * 2048 + aoff0);  \
        aF[1][f] = *(const bf16x8*)(Ah[buf] + ((mh)*4 + f) * 2048 + aoff1);  \
    }                                                                        \
} while (0)

#define READ_B(buf, nh) do {                                                 \
    _Pragma("unroll") for (int j = 0; j < 2; ++j) {                          \
        bF[nh][0][j] = *(const bf16x8*)(Bh[buf] + ((nh)*2 + j) * 2048 + aoff0); \
        bF[nh][1][j] = *(const bf16x8*)(Bh[buf] + ((nh)*2 + j) * 2048 + aoff1); \
    }                                                                        \
} while (0)

#define MFMA_Q(mh, nh) do {                                                  \
    _Pragma("unroll") for (int ks = 0; ks < 2; ++ks)                         \
    _Pragma("unroll") for (int j = 0; j < 2; ++j)                            \
    _Pragma("unroll") for (int f = 0; f < 4; ++f)                            \
        acc[(mh)*4 + f][(nh)*2 + j] = __builtin_amdgcn_mfma_f32_16x16x32_bf16( \
            aF[ks][f], bF[nh][ks][j], acc[(mh)*4 + f][(nh)*2 + j], 0, 0, 0); \
} while (0)

// barrier -> lgkmcnt(0) (+sched fence, rule #18) -> setprio'd MFMA -> barrier
#define PHASE_TAIL(MF) do {                                                  \
    __builtin_amdgcn_s_barrier();                                            \
    asm volatile("s_waitcnt lgkmcnt(0)" ::: "memory");                       \
    __builtin_amdgcn_sched_barrier(0);                                       \
    __builtin_amdgcn_s_setprio(1);                                           \
    MF;                                                                      \
    __builtin_amdgcn_s_setprio(0);                                           \
    __builtin_amdgcn_s_barrier();                                            \
} while (0)

    const int NT = K / BK;               // 64, even

    // ---- prologue: T0 (B0,B1,A0,A1) -> buf0, T1 (B0,B1) -> buf1 (12 loads)
    STAGE_B(0, 0, 0); STAGE_B(0, 1, 0);
    STAGE_A(0, 0, 0); STAGE_A(0, 1, 0);
    STAGE_B(1, 0, 1); STAGE_B(1, 1, 1);
    asm volatile("s_waitcnt vmcnt(4)" ::: "memory");   // T0 landed; T1.B in flight
    __builtin_amdgcn_s_barrier();

#pragma unroll 1
    for (int kt0 = 0; kt0 < NT; kt0 += 2) {
        const int t1 = kt0 + 1;
        const int t2 = (kt0 + 2 < NT) ? kt0 + 2 : NT - 1;
        const int t3 = (kt0 + 3 < NT) ? kt0 + 3 : NT - 1;

        // ---- K-tile T0 from buf0 ----
        READ_A(0, 0); READ_B(0, 0);          // 12 ds_read_b128
        STAGE_A(1, 0, t1);
        PHASE_TAIL(MFMA_Q(0, 0));            // ph1

        READ_B(0, 1);                        // 4
        STAGE_A(1, 1, t1);
        PHASE_TAIL(MFMA_Q(0, 1));            // ph2

        READ_A(0, 1);                        // 8
        STAGE_B(0, 0, t2);
        PHASE_TAIL(MFMA_Q(1, 1));            // ph3

        STAGE_B(0, 1, t2);
        asm volatile("s_waitcnt vmcnt(4)" ::: "memory");  // T1 fully landed
        PHASE_TAIL(MFMA_Q(1, 0));            // ph4

        // ---- K-tile T1 from buf1 ----
        READ_A(1, 0); READ_B(1, 0);
        STAGE_A(0, 0, t2);
        PHASE_TAIL(MFMA_Q(0, 0));            // ph5

        READ_B(1, 1);
        STAGE_A(0, 1, t2);
        PHASE_TAIL(MFMA_Q(0, 1));            // ph6

        READ_A(1, 1);
        STAGE_B(1, 0, t3);
        PHASE_TAIL(MFMA_Q(1, 1));            // ph7

        STAGE_B(1, 1, t3);
        asm volatile("s_waitcnt vmcnt(4)" ::: "memory");  // T2 fully landed
        PHASE_TAIL(MFMA_Q(1, 0));            // ph8
    }

    // drain outstanding prefetches before retiring (clamped tail stages)
    asm volatile("s_waitcnt vmcnt(0)" ::: "memory");

    // C/D layout (16x16x32): col = lane&15, row = (lane>>4)*4 + r
    const int crow = brow + wr * 128 + lg * 4;
    const int ccol = bcol + wc * 64 + l15;
#pragma unroll
    for (int f = 0; f < 8; ++f)
#pragma unroll
        for (int j = 0; j < 4; ++j)
#pragma unroll
            for (int r = 0; r < 4; ++r)
                C[(size_t)(crow + f * 16 + r) * N + (ccol + j * 16)] =
                    acc[f][j][r] * scale;

#undef STAGE_A
#undef STAGE_B
#undef READ_A
#undef READ_B
#undef MFMA_Q
#undef PHASE_TAIL
}

// ---------------------------------------------------------------------------
// Fallback if workspace too small: 128x128 tile, convert fp32->bf16 / sign
// during LDS staging (regular loads + ds_write). Slower but correct.
#define FBM 128
#define FBK 32

__global__ __launch_bounds__(256, 2)
void gemm_fused(const float* __restrict__ A32, const float* __restrict__ W32,
                float* __restrict__ C, int M, int N, int K, float scale)
{
    __shared__ u16 As[FBM * FBK];
    __shared__ u16 Bs[FBM * FBK];

    const int tid  = threadIdx.x;
    const int wave = tid >> 6;
    const int lane = tid & 63;

    const int brow = blockIdx.y * FBM;
    const int bcol = blockIdx.x * FBM;
    const int wrow = (wave >> 1) * 64;
    const int wcol = (wave & 1) * 64;

    f32x4 acc[4][4];
#pragma unroll
    for (int i = 0; i < 4; ++i)
#pragma unroll
        for (int j = 0; j < 4; ++j) acc[i][j] = (f32x4){0.f, 0.f, 0.f, 0.f};

    const int srow = tid >> 1;
    const int scol = (tid & 1) * 16;
    const float* Ag = A32 + (size_t)(brow + srow) * K + scol;
    const float* Wg = W32 + (size_t)(bcol + srow) * K + scol;
    u16* Asl = &As[srow * FBK + scol];
    u16* Bsl = &Bs[srow * FBK + scol];

    const int fm = lane & 15;
    const int fk = (lane >> 4) * 8;

    const int ktiles = K / FBK;
    for (int kt = 0; kt < ktiles; ++kt) {
        const float* ag = Ag + kt * FBK;
        const float* wg = Wg + kt * FBK;
        f32x4 a0 = *(const f32x4*)(ag + 0),  a1 = *(const f32x4*)(ag + 4);
        f32x4 a2 = *(const f32x4*)(ag + 8),  a3 = *(const f32x4*)(ag + 12);
        f32x4 w0 = *(const f32x4*)(wg + 0),  w1 = *(const f32x4*)(wg + 4);
        f32x4 w2 = *(const f32x4*)(wg + 8),  w3 = *(const f32x4*)(wg + 12);
        u16x8 pa0, pa1, pw0, pw1;
        pa0[0]=f2bf_rne(a0[0]); pa0[1]=f2bf_rne(a0[1]); pa0[2]=f2bf_rne(a0[2]); pa0[3]=f2bf_rne(a0[3]);
        pa0[4]=f2bf_rne(a1[0]); pa0[5]=f2bf_rne(a1[1]); pa0[6]=f2bf_rne(a1[2]); pa0[7]=f2bf_rne(a1[3]);
        pa1[0]=f2bf_rne(a2[0]); pa1[1]=f2bf_rne(a2[1]); pa1[2]=f2bf_rne(a2[2]); pa1[3]=f2bf_rne(a2[3]);
        pa1[4]=f2bf_rne(a3[0]); pa1[5]=f2bf_rne(a3[1]); pa1[6]=f2bf_rne(a3[2]); pa1[7]=f2bf_rne(a3[3]);
        pw0[0]=signbf(w0[0]); pw0[1]=signbf(w0[1]); pw0[2]=signbf(w0[2]); pw0[3]=signbf(w0[3]);
        pw0[4]=signbf(w1[0]); pw0[5]=signbf(w1[1]); pw0[6]=signbf(w1[2]); pw0[7]=signbf(w1[3]);
        pw1[0]=signbf(w2[0]); pw1[1]=signbf(w2[1]); pw1[2]=signbf(w2[2]); pw1[3]=signbf(w2[3]);
        pw1[4]=signbf(w3[0]); pw1[5]=signbf(w3[1]); pw1[6]=signbf(w3[2]); pw1[7]=signbf(w3[3]);
        *(u16x8*)Asl = pa0;  *(u16x8*)(Asl + 8) = pa1;
        *(u16x8*)Bsl = pw0;  *(u16x8*)(Bsl + 8) = pw1;
        __syncthreads();

        bf16x8 af[4], bv[4];
#pragma unroll
        for (int i = 0; i < 4; ++i)
            af[i] = *(const bf16x8*)&As[(wrow + i * 16 + fm) * FBK + fk];
#pragma unroll
        for (int j = 0; j < 4; ++j)
            bv[j] = *(const bf16x8*)&Bs[(wcol + j * 16 + fm) * FBK + fk];
#pragma unroll
        for (int i = 0; i < 4; ++i)
#pragma unroll
            for (int j = 0; j < 4; ++j)
                acc[i][j] = __builtin_amdgcn_mfma_f32_16x16x32_bf16(
                    af[i], bv[j], acc[i][j], 0, 0, 0);
        __syncthreads();
    }

    const int crow = brow + wrow + (lane >> 4) * 4;
    const int ccol = bcol + wcol + fm;
#pragma unroll
    for (int i = 0; i < 4; ++i)
#pragma unroll
        for (int j = 0; j < 4; ++j)
#pragma unroll
            for (int r = 0; r < 4; ++r)
                C[(size_t)(crow + i * 16 + r) * N + (ccol + j * 16)] =
                    acc[i][j][r] * scale;
}

// ---------------------------------------------------------------------------
extern "C" void kernel_launch(void* const* d_in, const int* in_sizes, int n_in,
                              void* d_out, int out_size, void* d_ws, size_t ws_size,
                              hipStream_t stream)
{
    const float* x = (const float*)d_in[0];   // [M][K] fp32
    const float* w = (const float*)d_in[1];   // [N][K] fp32
    float* out = (float*)d_out;               // [M][N] fp32

    const int K = 4096;
    const int M = in_sizes[0] / K;            // 8192
    const int N = in_sizes[1] / K;            // 4096
    const float scale = 1.0f / sqrtf((float)K);

    const size_t xbytes = (size_t)M * K * sizeof(u16);
    const size_t wbytes = (size_t)N * K * sizeof(u16);

    if (ws_size >= xbytes + wbytes && (M % BM) == 0 && (N % BN) == 0 &&
        (K % (2 * BK)) == 0) {
        u16* xb = (u16*)d_ws;
        u16* wb = (u16*)((char*)d_ws + xbytes);
        const long nx = (long)M * K;
        const long nw = (long)N * K;
        cvt_both<<<dim3(2048), dim3(256), 0, stream>>>(x, w, xb, wb, nx, nw);
        dim3 grid((M / BM) * (N / BN));       // 512 blocks, 1-D for XCD swizzle
        gemm_bt_256<<<grid, dim3(512), 0, stream>>>(xb, wb, out, M, N, K, scale);
    } else {
        dim3 grid(N / FBM, M / FBM);
        gemm_fused<<<grid, dim3(256), 0, stream>>>(x, w, out, M, N, K, scale);
    }
}